// Round 13
// baseline (510.462 us; speedup 1.0000x reference)
//
#include <hip/hip_runtime.h>

typedef unsigned short u16;
typedef unsigned int u32;
typedef __attribute__((ext_vector_type(4))) float f32x4;
typedef __bf16 bf16x8 __attribute__((ext_vector_type(8)));
typedef __attribute__((ext_vector_type(8))) unsigned short u16x8;

// ---------- small helpers ----------
__device__ __forceinline__ u16 f2bf(float x) {
    u32 u = __builtin_bit_cast(u32, x);
    u += 0x7FFFu + ((u >> 16) & 1u);   // RNE
    return (u16)(u >> 16);
}
__device__ __forceinline__ float bf2f(u16 u) {
    return __builtin_bit_cast(float, ((u32)u) << 16);
}
__device__ __forceinline__ void gld_lds16(void* lds, const void* g) {
    __builtin_amdgcn_global_load_lds(
        (const __attribute__((address_space(1))) void*)g,
        (__attribute__((address_space(3))) void*)lds, 16, 0, 0);
}

// bf16 pack locations inside an output row (u16 index into d_out viewed as u16).
__device__ __forceinline__ size_t pack_base_tail(long row) {
    return (size_t)row * 100514 + 59936 - ((row * 2) & 7);
}
__device__ __forceinline__ size_t pack_base_head(long row) {
    return (size_t)row * 100514 + 20480 - ((row * 2) & 7);
}

__device__ __forceinline__ void cvt_range(const float* __restrict__ src,
                                          u16* __restrict__ dst, int n,
                                          int bloc, int nb) {
    int i0 = bloc * 1024 + threadIdx.x * 4;
    int stride = nb * 1024;
    if (src) {
        for (int i = i0; i < n; i += stride) {
            float4 v = *(const float4*)(src + i);
            ushort4 o;
            o.x = f2bf(v.x); o.y = f2bf(v.y); o.z = f2bf(v.z); o.w = f2bf(v.w);
            *(ushort4*)(dst + i) = o;
        }
    } else {
        ushort4 z = {0, 0, 0, 0};
        for (int i = i0; i < n; i += stride) *(ushort4*)(dst + i) = z;
    }
}
__device__ __forceinline__ void cvt_range512(const float* __restrict__ src,
                                             u16* __restrict__ dst, int n,
                                             int bloc, int nb) {
    int i0 = bloc * 2048 + threadIdx.x * 4;
    int stride = nb * 2048;
    if (src) {
        for (int i = i0; i < n; i += stride) {
            float4 v = *(const float4*)(src + i);
            ushort4 o;
            o.x = f2bf(v.x); o.y = f2bf(v.y); o.z = f2bf(v.z); o.w = f2bf(v.w);
            *(ushort4*)(dst + i) = o;
        }
    } else {
        ushort4 z = {0, 0, 0, 0};
        for (int i = i0; i < n; i += stride) *(ushort4*)(dst + i) = z;
    }
}

// ---------- launch 1: small converts + pads + row map ----------
__global__ __launch_bounds__(256) void cvt1(const float* __restrict__ x,
                                            const float* __restrict__ hw,
                                            const float* __restrict__ t0a,
                                            const float* __restrict__ t1a,
                                            const float* __restrict__ t1b,
                                            const int* __restrict__ tgt,
                                            u16* __restrict__ XI, u16* __restrict__ HW,
                                            u16* __restrict__ TAB, u16* __restrict__ T1B,
                                            int* __restrict__ rowlist, int* __restrict__ cntbuf) {
    int b = blockIdx.x;
    if (b < 80)       { cvt_range(x,   XI,            2097152,  b,       80);  return; }
    if (b < 472)      { cvt_range(hw,  HW,            10242048, b - 80,  392); return; }
    if (b < 512)      { cvt_range(t0a, TAB,           1048576,  b - 472, 40);  return; }
    if (b < 522)      { cvt_range(t1a, TAB + 1048576, 262144,   b - 512, 10);  return; }
    if (b < 526)      { cvt_range(t1b, T1B,           65792,    b - 522, 4);   return; }
    if (b < 536)      { cvt_range(0,   HW + 10242048, 243712,   b - 526, 10);  return; }
    // b == 536: build row map
    __shared__ int cs[257];
    int t = threadIdx.x;
    int cnt_local = 0;
    int mk[8];
#pragma unroll
    for (int k = 0; k < 8; k++) {
        int tg = tgt[t * 8 + k];
        mk[k] = (tg >= 10000 && tg < 50000) ? 1 : 0;
        cnt_local += mk[k];
    }
    cs[t + 1] = cnt_local;
    __syncthreads();
    if (t == 0) {
        cs[0] = 0;
        for (int i = 1; i <= 256; i++) cs[i] += cs[i - 1];
        cntbuf[0] = cs[256];
        cntbuf[1] = (cs[256] + 255) & ~255;
    }
    __syncthreads();
    int cnt = cs[256];
    int offm = cs[t];
    int offu = cnt + (t * 8 - cs[t]);
#pragma unroll
    for (int k = 0; k < 8; k++) {
        if (mk[k]) rowlist[offm++] = t * 8 + k;
        else       rowlist[offu++] = t * 8 + k;
    }
}

// ---------- launch 2: proj GEMM + head GEMM + t0b convert, one 512-thread dispatch ----------
// y<5: proj (A=XI, B=TAB, plain bf16 out); y in [5,45): head (pack + partials);
// y in [45,74): t0b convert (224 blocks) + pad (8 blocks) — repacked so cvt block
// duration ~ GEMM block duration (even rounds).
__global__ __launch_bounds__(512, 1) void fused2(const u16* __restrict__ XI,
                                                 const u16* __restrict__ TAB,
                                                 const u16* __restrict__ HW,
                                                 u16* __restrict__ PROJ,
                                                 u16* __restrict__ outpk,
                                                 float* __restrict__ parth,
                                                 const float* __restrict__ t0b,
                                                 u16* __restrict__ T0B) {
    const int y = blockIdx.y;
    if (y >= 45) {
        int bc = (y - 45) * 8 + blockIdx.x;   // 0..231
        if (bc < 224) cvt_range512(t0b, T0B, 40960000, bc, 224);
        else          cvt_range512(0, T0B + 40960000, 196608, bc - 224, 8);
        return;
    }
    const bool proj = y < 5;
    const int NY = proj ? 5 : 40;
    const int l = (proj ? y : y - 5) * 8 + blockIdx.x;
    const int w = (l & 7) * NY + (l >> 3);
    const int m0 = (w & 7) * 256, n0 = (w >> 3) * 256;
    const u16* B = proj ? TAB : HW;
    __shared__ u16 lds[65536];
    const int tid = threadIdx.x;
    const int lane = tid & 63, wv = tid >> 6;
    const int wm = wv >> 2, wn = wv & 3;
    const int lr = lane & 15, hi = lane >> 4;

    const int rp = ((tid >> 7) << 4) + (tid & 15);
    const int kp = ((tid >> 4) & 7) * 8;
    const u16 *pA[2][2], *pB[2][2];
#pragma unroll
    for (int h = 0; h < 2; h++) {
#pragma unroll
        for (int c = 0; c < 2; c++) {
            int row = h * 128 + rp + c * 64;
            pA[h][c] = XI + (size_t)(m0 + row) * 1024 + kp;
            pB[h][c] = B + (size_t)(n0 + row) * 1024 + kp;
        }
    }

    f32x4 acc[8][4] = {};
    bf16x8 Bf[4][2], Af[2][2];

    auto stA = [&](int s, int h, int t) {
        u16* d = lds + s * 16384 + h * 8192 + tid * 8;
        int ko = t * 64;
        gld_lds16(d, pA[h][0] + ko);
        gld_lds16(d + 4096, pA[h][1] + ko);
    };
    auto stB = [&](int s, int h, int t) {
        u16* d = lds + 32768 + s * 16384 + h * 8192 + tid * 8;
        int ko = t * 64;
        gld_lds16(d, pB[h][0] + ko);
        gld_lds16(d + 4096, pB[h][1] + ko);
    };
    auto rdB = [&](int s) {
        const u16* base = lds + 32768 + s * 16384 + (wn >> 1) * 8192 + (wn & 1) * 4096 + hi * 128 + lr * 8;
#pragma unroll
        for (int j = 0; j < 4; j++)
#pragma unroll
            for (int ks = 0; ks < 2; ks++)
                Bf[j][ks] = *(const bf16x8*)(base + j * 1024 + ks * 512);
    };
    auto rdA = [&](int s, int p) {
        const u16* base = lds + s * 16384 + wm * 8192 + p * 2048 + hi * 128 + lr * 8;
#pragma unroll
        for (int m = 0; m < 2; m++)
#pragma unroll
            for (int ks = 0; ks < 2; ks++)
                Af[m][ks] = *(const bf16x8*)(base + m * 1024 + ks * 512);
    };
    auto mf = [&](int p) {
        __builtin_amdgcn_s_setprio(1);
#pragma unroll
        for (int m = 0; m < 2; m++)
#pragma unroll
            for (int j = 0; j < 4; j++)
#pragma unroll
                for (int ks = 0; ks < 2; ks++)
                    acc[p * 2 + m][j] = __builtin_amdgcn_mfma_f32_16x16x32_bf16(
                        Af[m][ks], Bf[j][ks], acc[p * 2 + m][j], 0, 0, 0);
        __builtin_amdgcn_s_setprio(0);
    };

#define BAR_()   __builtin_amdgcn_s_barrier()
#define LGKM0_() do { asm volatile("s_waitcnt lgkmcnt(0)" ::: "memory"); \
                      __builtin_amdgcn_sched_barrier(0); } while (0)
#define VM4_()   asm volatile("s_waitcnt vmcnt(4)" ::: "memory")
#define VM0_()   asm volatile("s_waitcnt vmcnt(0)" ::: "memory")

    stA(0, 0, 0); stA(0, 1, 0); stB(0, 0, 0); stB(0, 1, 0);
    VM0_();
    stB(1, 0, 1); stB(1, 1, 1);
    BAR_();

    auto iter = [&](int t0, bool full) {
        rdB(0); rdA(0, 0);
        stA(1, 0, t0 + 1);
        BAR_(); LGKM0_(); mf(0); BAR_();
        rdA(0, 1);
        stA(1, 1, t0 + 1);
        __builtin_amdgcn_sched_barrier(0);
        if (full) stB(0, 0, t0 + 2);
        BAR_(); LGKM0_(); mf(1); BAR_();
        rdA(0, 2);
        if (full) stB(0, 1, t0 + 2);
        BAR_(); LGKM0_(); mf(2); BAR_();
        rdA(0, 3);
        if (full) { VM4_(); } else { VM0_(); }
        BAR_(); LGKM0_(); mf(3); BAR_();
        rdB(1); rdA(1, 0);
        if (full) stA(0, 0, t0 + 2);
        BAR_(); LGKM0_(); mf(0); BAR_();
        rdA(1, 1);
        if (full) { stA(0, 1, t0 + 2);
                    __builtin_amdgcn_sched_barrier(0);
                    stB(1, 0, t0 + 3); }
        BAR_(); LGKM0_(); mf(1); BAR_();
        rdA(1, 2);
        if (full) stB(1, 1, t0 + 3);
        BAR_(); LGKM0_(); mf(2); BAR_();
        rdA(1, 3);
        if (full) VM4_();
        BAR_(); LGKM0_(); mf(3); BAR_();
    };
#pragma unroll 1
    for (int i = 0; i < 7; i++) iter(2 * i, true);
    iter(14, false);

#undef BAR_
#undef LGKM0_
#undef VM4_
#undef VM0_

    const int cr = hi * 4, cc = lr;
    if (proj) {
#pragma unroll
        for (int m = 0; m < 8; m++)
#pragma unroll
            for (int q = 0; q < 4; q++) {
                int r = m0 + wm * 128 + m * 16 + cr + q;
#pragma unroll
                for (int j = 0; j < 4; j++)
                    PROJ[(size_t)r * 1280 + n0 + wn * 64 + j * 16 + cc] = f2bf(acc[m][j][q]);
            }
        return;
    }
#pragma unroll
    for (int m = 0; m < 8; m++) {
#pragma unroll
        for (int q = 0; q < 4; q++) {
            int r = m0 + wm * 128 + m * 16 + cr + q;
            u16* dst = outpk + pack_base_head((long)r) + n0 + wn * 64 + cc;
            float s = 0.f;
#pragma unroll
            for (int j = 0; j < 4; j++) {
                float v = acc[m][j][q];
                dst[j * 16] = f2bf(v);
                int col = n0 + wn * 64 + j * 16 + cc;
                s += (col < 10002) ? __expf(v) : 0.f;
            }
            s += __shfl_xor(s, 1); s += __shfl_xor(s, 2);
            s += __shfl_xor(s, 4); s += __shfl_xor(s, 8);
            if (cc == 0) parth[(size_t)r * 160 + (n0 >> 6) + wn] = s;
        }
    }
}

// ---------- launch 3: tail0 GEMM (compile-time specialized, R11-verified) ----------
template <int TAIL>
__global__ __launch_bounds__(512, 1) void gemm256p(const u16* __restrict__ A,
                                                   const u16* __restrict__ B,
                                                   u16* __restrict__ outpk,
                                                   const int* __restrict__ rowlist,
                                                   const int* __restrict__ cntbuf,
                                                   float* __restrict__ part) {
    const int NY = TAIL ? 157 : 40;
    const int l = blockIdx.y * 8 + blockIdx.x;
    const int w = (l & 7) * NY + (l >> 3);
    const int m0 = (w & 7) * 256, n0 = (w >> 3) * 256;
    if (TAIL) { if (m0 >= cntbuf[1]) return; }
    __shared__ u16 lds[65536];
    const int tid = threadIdx.x;
    const int lane = tid & 63, wv = tid >> 6;
    const int wm = wv >> 2, wn = wv & 3;
    const int lr = lane & 15, hi = lane >> 4;

    const int rp = ((tid >> 7) << 4) + (tid & 15);
    const int kp = ((tid >> 4) & 7) * 8;
    const u16 *pA[2][2], *pB[2][2];
#pragma unroll
    for (int h = 0; h < 2; h++) {
#pragma unroll
        for (int c = 0; c < 2; c++) {
            int row = h * 128 + rp + c * 64;
            if (TAIL) pA[h][c] = A + (size_t)rowlist[m0 + row] * 1280 + kp;
            else      pA[h][c] = A + (size_t)(m0 + row) * 1024 + kp;
            pB[h][c] = B + (size_t)(n0 + row) * 1024 + kp;
        }
    }

    f32x4 acc[8][4] = {};
    bf16x8 Bf[4][2], Af[2][2];

    auto stA = [&](int s, int h, int t) {
        u16* d = lds + s * 16384 + h * 8192 + tid * 8;
        int ko = t * 64;
        gld_lds16(d, pA[h][0] + ko);
        gld_lds16(d + 4096, pA[h][1] + ko);
    };
    auto stB = [&](int s, int h, int t) {
        u16* d = lds + 32768 + s * 16384 + h * 8192 + tid * 8;
        int ko = t * 64;
        gld_lds16(d, pB[h][0] + ko);
        gld_lds16(d + 4096, pB[h][1] + ko);
    };
    auto rdB = [&](int s) {
        const u16* base = lds + 32768 + s * 16384 + (wn >> 1) * 8192 + (wn & 1) * 4096 + hi * 128 + lr * 8;
#pragma unroll
        for (int j = 0; j < 4; j++)
#pragma unroll
            for (int ks = 0; ks < 2; ks++)
                Bf[j][ks] = *(const bf16x8*)(base + j * 1024 + ks * 512);
    };
    auto rdA = [&](int s, int p) {
        const u16* base = lds + s * 16384 + wm * 8192 + p * 2048 + hi * 128 + lr * 8;
#pragma unroll
        for (int m = 0; m < 2; m++)
#pragma unroll
            for (int ks = 0; ks < 2; ks++)
                Af[m][ks] = *(const bf16x8*)(base + m * 1024 + ks * 512);
    };
    auto mf = [&](int p) {
        __builtin_amdgcn_s_setprio(1);
#pragma unroll
        for (int m = 0; m < 2; m++)
#pragma unroll
            for (int j = 0; j < 4; j++)
#pragma unroll
                for (int ks = 0; ks < 2; ks++)
                    acc[p * 2 + m][j] = __builtin_amdgcn_mfma_f32_16x16x32_bf16(
                        Af[m][ks], Bf[j][ks], acc[p * 2 + m][j], 0, 0, 0);
        __builtin_amdgcn_s_setprio(0);
    };

#define BAR_()   __builtin_amdgcn_s_barrier()
#define LGKM0_() do { asm volatile("s_waitcnt lgkmcnt(0)" ::: "memory"); \
                      __builtin_amdgcn_sched_barrier(0); } while (0)
#define VM4_()   asm volatile("s_waitcnt vmcnt(4)" ::: "memory")
#define VM0_()   asm volatile("s_waitcnt vmcnt(0)" ::: "memory")

    stA(0, 0, 0); stA(0, 1, 0); stB(0, 0, 0); stB(0, 1, 0);
    VM0_();
    stB(1, 0, 1); stB(1, 1, 1);
    BAR_();

    auto iter = [&](int t0, bool full) {
        rdB(0); rdA(0, 0);
        stA(1, 0, t0 + 1);
        BAR_(); LGKM0_(); mf(0); BAR_();
        rdA(0, 1);
        stA(1, 1, t0 + 1);
        __builtin_amdgcn_sched_barrier(0);
        if (full) stB(0, 0, t0 + 2);
        BAR_(); LGKM0_(); mf(1); BAR_();
        rdA(0, 2);
        if (full) stB(0, 1, t0 + 2);
        BAR_(); LGKM0_(); mf(2); BAR_();
        rdA(0, 3);
        if (full) { VM4_(); } else { VM0_(); }
        BAR_(); LGKM0_(); mf(3); BAR_();
        rdB(1); rdA(1, 0);
        if (full) stA(0, 0, t0 + 2);
        BAR_(); LGKM0_(); mf(0); BAR_();
        rdA(1, 1);
        if (full) { stA(0, 1, t0 + 2);
                    __builtin_amdgcn_sched_barrier(0);
                    stB(1, 0, t0 + 3); }
        BAR_(); LGKM0_(); mf(1); BAR_();
        rdA(1, 2);
        if (full) stB(1, 1, t0 + 3);
        BAR_(); LGKM0_(); mf(2); BAR_();
        rdA(1, 3);
        if (full) VM4_();
        BAR_(); LGKM0_(); mf(3); BAR_();
    };
#pragma unroll 1
    for (int i = 0; i < 7; i++) iter(2 * i, true);
    iter(14, false);

#undef BAR_
#undef LGKM0_
#undef VM4_
#undef VM0_

    const int cr = hi * 4, cc = lr;
    const int climit = TAIL ? 40000 : 10002;
    const int pstride = TAIL ? 628 : 160;
#pragma unroll
    for (int m = 0; m < 8; m++) {
#pragma unroll
        for (int q = 0; q < 4; q++) {
            int r = m0 + wm * 128 + m * 16 + cr + q;
            long orow = TAIL ? rowlist[r] : r;
            size_t base = TAIL ? pack_base_tail(orow) : pack_base_head(orow);
            u16* dst = outpk + base + n0 + wn * 64 + cc;
            float s = 0.f;
#pragma unroll
            for (int j = 0; j < 4; j++) {
                float v = acc[m][j][q];
                dst[j * 16] = f2bf(v);
                int col = n0 + wn * 64 + j * 16 + cc;
                s += (col < climit) ? __expf(v) : 0.f;
            }
            s += __shfl_xor(s, 1); s += __shfl_xor(s, 2);
            s += __shfl_xor(s, 4); s += __shfl_xor(s, 8);
            if (cc == 0) part[(size_t)r * pstride + (n0 >> 6) + wn] = s;
        }
    }
}

// ---------- launch 4: all normalization, 512 threads, one block per compact slot ----------
__global__ __launch_bounds__(512) void norm_all(float* __restrict__ out,
                                                const int* __restrict__ tgt,
                                                const int* __restrict__ rowlist,
                                                const int* __restrict__ cntbuf,
                                                const float* __restrict__ PARTH,
                                                const float* __restrict__ PART,
                                                const u16* __restrict__ proj,
                                                const u16* __restrict__ t1b) {
    const int b = blockIdx.x, tid = threadIdx.x;
    const int wv = tid >> 6;
    const int cnt = cntbuf[0];
    const long row = rowlist[b];
    __shared__ float red[8];
    __shared__ float pr[256];
    __shared__ float lg[257];
    float* p0 = out + (size_t)row * 50257;

    // --- phase 1: head (reduce 160 partials; expand 10002 cols; grab priors) ---
    float s = (tid < 160) ? PARTH[(size_t)row * 160 + tid] : 0.f;
#pragma unroll
    for (int o = 32; o; o >>= 1) s += __shfl_xor(s, o);
    if ((tid & 63) == 0) red[wv] = s;
    __syncthreads();
    float logZh = __logf(red[0] + red[1] + red[2] + red[3] +
                         red[4] + red[5] + red[6] + red[7]);
    const u16* pkh = (const u16*)out + pack_base_head(row);
    float prior0 = bf2f(pkh[9999]) - logZh;
    float l1 = bf2f(pkh[10000]) - logZh;
    float l2 = bf2f(pkh[10001]) - logZh;
#pragma unroll
    for (int k = 0; k < 3; k++) {
        int c0 = k * 4096 + tid * 8;
        if (c0 + 8 <= 10002) {
            u16x8 xv = *(const u16x8*)(pkh + c0);
#pragma unroll
            for (int z = 0; z < 8; z++) p0[c0 + z] = bf2f(xv[z]) - logZh;
        } else if (c0 < 10002) {
            for (int z = 0; c0 + z < 10002; z++) p0[c0 + z] = bf2f(pkh[c0 + z]) - logZh;
        }
    }
    __syncthreads();

    // --- phase 2: tail0 (10 chunks of 4096; read-before-write verified for c<=9) ---
    float* p = p0 + 10000;
    if (b < cnt) {
        float s2 = 0.f;
        for (int c = tid; c < 628; c += 512) s2 += PART[(size_t)b * 628 + c];
#pragma unroll
        for (int o = 32; o; o >>= 1) s2 += __shfl_xor(s2, o);
        if ((tid & 63) == 0) red[wv] = s2;
        __syncthreads();
        float Aa = __logf(red[0] + red[1] + red[2] + red[3] +
                          red[4] + red[5] + red[6] + red[7]) - prior0;
        const u16* src = (const u16*)out + pack_base_tail(row);
#pragma unroll 1
        for (int c = 0; c < 10; c++) {
            int nelem = (c == 9) ? 3136 : 4096;
            bool act = tid * 8 < nelem;
            float v[8];
            if (act) {
                u16x8 xv = *(const u16x8*)(src + 4096 * c + tid * 8);
#pragma unroll
                for (int z = 0; z < 8; z++) v[z] = bf2f(xv[z]);
            }
            __syncthreads();
            if (act) {
                int e = 4096 * c + tid * 8;
#pragma unroll
                for (int z = 0; z < 8; z++) p[e + z] = v[z] - Aa;
            }
            __syncthreads();
        }
    } else {
        for (int e = tid; e < 40000; e += 512) p[e] = 0.f;
        if (tid == 0) { p[0] = l1; p[1] = l2; }
        __syncthreads();
    }

    // --- phase 3: tail1 ---
    float* p5 = p0 + 50000;
    int t = tgt[row];
    if (t < 50000) {
        for (int c = tid; c < 257; c += 512) p5[c] = 0.f;
        return;
    }
    if (tid < 256) pr[tid] = bf2f(proj[(size_t)row * 1280 + 1024 + tid]);
    __syncthreads();
    for (int c = tid; c < 257; c += 512) {
        const u16* wp = t1b + c * 256;
        float acc = 0.f;
        for (int k = 0; k < 256; k++) acc += bf2f(wp[k]) * pr[k];
        lg[c] = acc;
    }
    __syncthreads();
    float s1 = 0.f;
    for (int c = tid; c < 257; c += 512) s1 += __expf(lg[c]);
#pragma unroll
    for (int o = 32; o; o >>= 1) s1 += __shfl_xor(s1, o);
    if ((tid & 63) == 0) red[wv] = s1;
    __syncthreads();
    float A = __logf(red[0] + red[1] + red[2] + red[3] +
                     red[4] + red[5] + red[6] + red[7]) - l1;  // logZ - prior1
    for (int c = tid; c < 257; c += 512) p5[c] = lg[c] - A;
}

// ---------- workspace layout (bytes) ----------
#define OFF_XI    0UL              // 2048*1024*2    = 4,194,304
#define OFF_HEADW 4194304UL        // 10240*1024*2   = 20,971,520
#define OFF_TAB   25165824UL       // 1280*1024*2    = 2,621,440
#define OFF_T0B   27787264UL       // 40192*1024*2   = 82,313,216
#define OFF_T1B   110100480UL      // 257*256*2      = 131,584
#define OFF_PROJ  110232064UL      // 2048*1280*2    = 5,242,880
#define OFF_PART  115474944UL      // 2048*628*4     = 5,144,576
#define OFF_PARTH 120619520UL      // 2048*160*4     = 1,310,720
#define OFF_MAP   121930240UL      // 2048*4
#define OFF_CNT   121938432UL      // 64

extern "C" void kernel_launch(void* const* d_in, const int* in_sizes, int n_in,
                              void* d_out, int out_size, void* d_ws, size_t ws_size,
                              hipStream_t stream) {
    const float* x   = (const float*)d_in[0];
    const int*   tgt = (const int*)d_in[1];
    const float* hw  = (const float*)d_in[2];
    const float* t0a = (const float*)d_in[3];
    const float* t0b = (const float*)d_in[4];
    const float* t1a = (const float*)d_in[5];
    const float* t1b = (const float*)d_in[6];
    float* out = (float*)d_out;
    char* ws = (char*)d_ws;

    u16* XI     = (u16*)(ws + OFF_XI);
    u16* HW     = (u16*)(ws + OFF_HEADW);
    u16* TAB    = (u16*)(ws + OFF_TAB);
    u16* T0B    = (u16*)(ws + OFF_T0B);
    u16* T1B    = (u16*)(ws + OFF_T1B);
    u16* PROJ   = (u16*)(ws + OFF_PROJ);
    float* PART = (float*)(ws + OFF_PART);
    float* PARTH = (float*)(ws + OFF_PARTH);
    int* MAP    = (int*)(ws + OFF_MAP);
    int* CNT    = (int*)(ws + OFF_CNT);

    // 1) small converts + pads + row map
    cvt1<<<537, 256, 0, stream>>>(x, hw, t0a, t1a, t1b, tgt, XI, HW, TAB, T1B, MAP, CNT);

    // 2) proj GEMM + head GEMM + t0b convert, one dispatch (repacked cvt portion)
    fused2<<<dim3(8, 74), 512, 0, stream>>>(XI, TAB, HW, PROJ, (u16*)d_out, PARTH, t0b, T0B);

    // 3) tail0 GEMM (256^2 8-phase, XCD-swizzled, rowlist-gathered A)
    gemm256p<1><<<dim3(8, 157), 512, 0, stream>>>(PROJ, T0B, (u16*)d_out, MAP, CNT, PART);

    // 4) all normalization (head expand, tail0 expand/zero, tail1), 512 threads
    norm_all<<<2048, 512, 0, stream>>>(out, tgt, MAP, CNT, PARTH, PART, PROJ, T1B);
}